// Round 7
// baseline (304.449 us; speedup 1.0000x reference)
//
#include <hip/hip_runtime.h>
#include <hip/hip_bf16.h>

// ---------------------------------------------------------------------------
// Fused FlaxLLaMAAttention for MI355X (gfx950).
// B=1 S=2048 D=2048 H=32 KVH=8 HD=64, fp32 in/out, bf16 MFMA internals.
//
// Round 4 (3rd resubmit; rounds 4/5/6 benches were infra failures):
//  - k_attn: one (head, q-block) per wave (2048 waves, 2/SIMD), descending-
//    work dispatch, K+V prefetch software pipeline, exp2-domain softmax
//    (log2e folded into Q scale), s_setprio around MFMA clusters.
//  - k_gemm: 8-wave 128x128 tile, double-buffered LDS, prefetch-next-tile
//    global_load_lds issued BEFORE compute (T3 minimum 2-phase recipe).
// ---------------------------------------------------------------------------

using short8  = __attribute__((ext_vector_type(8))) short;
using f32x4   = __attribute__((ext_vector_type(4))) float;
using f32x16  = __attribute__((ext_vector_type(16))) float;
using f32x2   = __attribute__((ext_vector_type(2))) float;
using ushort4v= __attribute__((ext_vector_type(4))) unsigned short;

#define SEQ 2048
#define DIM 2048
#define NH  32
#define NKVH 8
#define HD  64
#define KVD 512      // NKVH*HD
#define NQKV 3072    // DIM + 2*KVD

#define GLOAD_LDS16(g, l) \
  __builtin_amdgcn_global_load_lds((const __attribute__((address_space(1))) void*)(g), \
                                   (__attribute__((address_space(3))) void*)(l), 16, 0, 0)

__device__ __forceinline__ float bf2f(unsigned short u) {
  union { float f; unsigned v; } x; x.v = ((unsigned)u) << 16; return x.f;
}
__device__ __forceinline__ unsigned short f2bf(float f) {
  union { float f; unsigned v; } x; x.f = f;
  unsigned r = x.v + 0x7fffu + ((x.v >> 16) & 1u);   // round-nearest-even
  return (unsigned short)(r >> 16);
}

// ---------------- elementwise cast fp32 -> bf16 (vectorized) ----------------
__global__ __launch_bounds__(256) void k_cast(const float* __restrict__ src,
                                              unsigned short* __restrict__ dst, int n) {
  int idx = (blockIdx.x * 256 + threadIdx.x) * 4;
  if (idx < n) {
    f32x4 v = *(const f32x4*)(src + idx);
    ushort4v o;
    o[0] = f2bf(v[0]); o[1] = f2bf(v[1]); o[2] = f2bf(v[2]); o[3] = f2bf(v[3]);
    *(ushort4v*)(dst + idx) = o;
  }
}

// ---------------- transpose + cast: src fp32 [R=2048][C] -> dst bf16 [C][2048]
__global__ __launch_bounds__(256) void k_tcast(const float* __restrict__ src, int C,
                                               unsigned short* __restrict__ dst) {
  __shared__ float tile[32][33];
  int c0 = blockIdx.x * 32, r0 = blockIdx.y * 32;
  int tx = threadIdx.x, ty = threadIdx.y;   // 32x8
  #pragma unroll
  for (int j = 0; j < 32; j += 8)
    tile[ty + j][tx] = src[(r0 + ty + j) * C + c0 + tx];
  __syncthreads();
  #pragma unroll
  for (int j = 0; j < 32; j += 8)
    dst[(c0 + ty + j) * 2048 + r0 + tx] = f2bf(tile[tx][ty + j]);
}

// ---------------- rope cos/sin table: tab[s][p] = (cos,sin)(pos[s]*freq_p) ---
__global__ __launch_bounds__(256) void k_table(const int* __restrict__ pos,
                                               f32x2* __restrict__ tab) {
  int i = blockIdx.x * 256 + threadIdx.x;   // 2048*32
  int s = i >> 5, p = i & 31;
  float freq = powf(10000.0f, -(float)(2 * p) / 64.0f);
  float ang = (float)pos[s] * freq;
  float sv, cv; sincosf(ang, &sv, &cv);
  f32x2 r; r[0] = cv; r[1] = sv;
  tab[i] = r;
}

// ---------------- bf16 GEMM: C[M=2048][N] = A[2048][2048] * Bt[N][2048]^T ----
// 128x128 tile, BK=64, 8 waves (2x4, each 64x32 out), 16x16x32 bf16 MFMA,
// double-buffered LDS with prefetch-before-compute (T3 minimum 2-phase).
template <int N, bool OUTF32>
__global__ __launch_bounds__(512) void k_gemm(const unsigned short* __restrict__ A,
                                              const unsigned short* __restrict__ Bt,
                                              void* __restrict__ Cout) {
  const int K = 2048;
  __shared__ unsigned short lA[2][128 * 64];
  __shared__ unsigned short lB[2][128 * 64];
  int m0 = blockIdx.y * 128, n0 = blockIdx.x * 128;
  int t = threadIdx.x, lane = t & 63, wid = t >> 6;
  int wr = wid >> 2, wc = wid & 3;          // wave 64x32 sub-tile
  int lr = lane & 15, lg = lane >> 4;

  f32x4 acc[4][2] = {};

  auto stage = [&](int k0, int buf) {
    #pragma unroll
    for (int j = 0; j < 2; ++j) {
      int idx = t + 512 * j, row = idx >> 3, c8 = idx & 7;
      GLOAD_LDS16(A  + (m0 + row) * K + k0 + c8 * 8, &lA[buf][idx * 8]);
      GLOAD_LDS16(Bt + (n0 + row) * K + k0 + c8 * 8, &lB[buf][idx * 8]);
    }
  };

  stage(0, 0);
  __syncthreads();                            // drain tile-0 staging
  int cur = 0;
  for (int k0 = 0; k0 < K; k0 += 64) {
    int kn = k0 + 64;
    if (kn < K) stage(kn, cur ^ 1);           // issue next tile (flies under MFMA)
    __builtin_amdgcn_s_setprio(1);
    #pragma unroll
    for (int kk = 0; kk < 64; kk += 32) {
      short8 af[4], bfr[2];
      #pragma unroll
      for (int i = 0; i < 4; ++i)
        af[i]  = *(const short8*)(&lA[cur][(wr * 64 + i * 16 + lr) * 64 + kk + lg * 8]);
      #pragma unroll
      for (int j = 0; j < 2; ++j)
        bfr[j] = *(const short8*)(&lB[cur][(wc * 32 + j * 16 + lr) * 64 + kk + lg * 8]);
      #pragma unroll
      for (int i = 0; i < 4; ++i)
        #pragma unroll
        for (int j = 0; j < 2; ++j)
          acc[i][j] = __builtin_amdgcn_mfma_f32_16x16x32_bf16(af[i], bfr[j], acc[i][j], 0, 0, 0);
    }
    __builtin_amdgcn_s_setprio(0);
    __syncthreads();                          // drain prefetch + all reads done
    cur ^= 1;
  }
  // epilogue: C layout col=lane&15, row=(lane>>4)*4+reg  [verified m89/m91]
  #pragma unroll
  for (int i = 0; i < 4; ++i)
    #pragma unroll
    for (int j = 0; j < 2; ++j)
      #pragma unroll
      for (int r = 0; r < 4; ++r) {
        int row = m0 + wr * 64 + i * 16 + lg * 4 + r;
        int col = n0 + wc * 32 + j * 16 + lr;
        float v = acc[i][j][r];
        if constexpr (OUTF32) ((float*)Cout)[row * N + col] = v;
        else ((unsigned short*)Cout)[row * N + col] = f2bf(v);
      }
}

// ---------------- rope split: xqkv -> xq (roped, *0.125*log2e), xk (roped) ---
// Q additionally scaled by log2(e) so attention softmax can use exp2 directly.
__global__ __launch_bounds__(256) void k_rope(const unsigned short* __restrict__ xqkv,
                                              const f32x2* __restrict__ tab,
                                              unsigned short* __restrict__ xq,
                                              unsigned short* __restrict__ xk) {
  int s = blockIdx.y;
  int j = blockIdx.x * 256 + threadIdx.x;   // 0..1279 pair index
  bool isq = j < 1024;
  int col = isq ? (2 * j) : (DIM + 2 * (j - 1024));
  int p = (col >> 1) & 31;
  f32x2 cs = tab[s * 32 + p];
  unsigned both = *(const unsigned*)(xqkv + s * NQKV + col);
  float a = bf2f((unsigned short)(both & 0xffff));
  float b = bf2f((unsigned short)(both >> 16));
  float ra = a * cs[0] - b * cs[1];
  float rb = a * cs[1] + b * cs[0];
  const float QS = 0.125f * 1.44269504088896f;  // 1/sqrt(64) * log2(e)
  if (isq) { ra *= QS; rb *= QS; }
  unsigned pk = (unsigned)f2bf(ra) | ((unsigned)f2bf(rb) << 16);
  if (isq) *(unsigned*)(xq + s * DIM + col) = pk;
  else     *(unsigned*)(xk + s * KVD + (col - DIM)) = pk;
}

// ---------------- v transpose: xqkv cols [2560,3072) -> xvT [512][2048] ------
__global__ __launch_bounds__(256) void k_vt(const unsigned short* __restrict__ xqkv,
                                            unsigned short* __restrict__ xvT) {
  __shared__ unsigned short tile[32][33];
  int c0 = blockIdx.x * 32, s0 = blockIdx.y * 32;
  int tx = threadIdx.x, ty = threadIdx.y;   // 32x8
  #pragma unroll
  for (int j = 0; j < 32; j += 8)
    tile[ty + j][tx] = xqkv[(s0 + ty + j) * NQKV + 2560 + c0 + tx];
  __syncthreads();
  #pragma unroll
  for (int j = 0; j < 32; j += 8)
    xvT[(c0 + ty + j) * SEQ + s0 + tx] = tile[tx][ty + j];
}

// ---------------- causal GQA flash attention (swapped-QK, in-register) ------
// 2048 waves: one (head, q-block of 32) each; grid ordered qb-descending so
// long blocks dispatch first. 4 waves/block share (kvh, qb) -> same K/V lines.
// Per 32-kv step: S^T = mfma32x32x16(K,Q); softmax in-register in exp2 domain;
// next step's K AND V prefetched before compute (latency hides under MFMA+VALU).
__global__ __launch_bounds__(256) void k_attn(const unsigned short* __restrict__ xq,
                                              const unsigned short* __restrict__ xk,
                                              const unsigned short* __restrict__ xvT,
                                              unsigned short* __restrict__ attnout) {
  int wid = threadIdx.x >> 6, lane = threadIdx.x & 63;
  int kvh = blockIdx.x & 7;
  int qb = 63 - (blockIdx.x >> 3);          // descending work order
  int h = kvh * 4 + wid;
  int lq = lane & 31, hi = lane >> 5;
  int q0 = qb * 32;

  // Q B-frags: lane holds q-row q0+lq, k = s*16 + hi*8 + [0..7]
  short8 qf[4];
  #pragma unroll
  for (int s = 0; s < 4; ++s)
    qf[s] = *(const short8*)(xq + (q0 + lq) * DIM + h * HD + s * 16 + hi * 8);

  f32x16 o0 = {}, o1 = {};                  // O[q(reg)][d = half*32 + lq]
  float m = -3.0e38f, l = 0.0f;

  auto loadK = [&](int kv0, short8* d) {
    #pragma unroll
    for (int s = 0; s < 4; ++s)
      d[s] = *(const short8*)(xk + (kv0 + lq) * KVD + kvh * HD + s * 16 + hi * 8);
  };
  auto loadV = [&](int kv0, short8* d) {
    #pragma unroll
    for (int s2 = 0; s2 < 2; ++s2) {
      d[s2 * 2 + 0] = *(const short8*)(xvT + (kvh * HD + lq)      * SEQ + kv0 + s2 * 16 + hi * 8);
      d[s2 * 2 + 1] = *(const short8*)(xvT + (kvh * HD + 32 + lq) * SEQ + kv0 + s2 * 16 + hi * 8);
    }
  };

  short8 kf[4], vf[4];
  loadK(0, kf); loadV(0, vf);

  for (int kv0 = 0; kv0 <= q0; kv0 += 32) {
    // prefetch next step (clamped; garbage never consumed on last iter)
    int kvn = min(kv0 + 32, q0);
    short8 kn[4], vn[4];
    loadK(kvn, kn); loadV(kvn, vn);

    // --- S^T = K Q^T : col=lq(q), row(kv) = (r&3)+8*(r>>2)+4*hi ---
    f32x16 st = {};
    __builtin_amdgcn_s_setprio(1);
    #pragma unroll
    for (int s = 0; s < 4; ++s)
      st = __builtin_amdgcn_mfma_f32_32x32x16_bf16(kf[s], qf[s], st, 0, 0, 0);
    __builtin_amdgcn_s_setprio(0);

    // --- causal mask: only the diagonal block is partial ---
    if (kv0 == q0) {
      #pragma unroll
      for (int r = 0; r < 16; ++r) {
        int kvl = (r & 3) + 8 * (r >> 2) + 4 * hi;
        if (kvl > lq) st[r] = -3.0e38f;
      }
    }
    // --- row max (lane owns q=lq; own 16 kv + partner half) ---
    float pmax = st[0];
    #pragma unroll
    for (int r = 1; r < 16; ++r) pmax = fmaxf(pmax, st[r]);
    pmax = fmaxf(pmax, __shfl_xor(pmax, 32));
    // --- defer-max rescale (bound 2^11.54 ~= e^8) ---
    if (!__all(pmax - m <= 11.54f)) {
      float mnew = fmaxf(m, pmax);
      float scale = exp2f(m - mnew);
      #pragma unroll
      for (int r = 0; r < 16; ++r) {
        int ql = (r & 3) + 8 * (r >> 2) + 4 * hi;
        float sc = __shfl(scale, ql);
        o0[r] *= sc; o1[r] *= sc;
      }
      l *= scale;
      m = mnew;
    }
    // --- P = exp2(S' - m), partial row-sum (S' already in log2 units) ---
    float p[16], sum = 0.0f;
    #pragma unroll
    for (int r = 0; r < 16; ++r) { p[r] = exp2f(st[r] - m); sum += p[r]; }
    l += sum;
    // --- pack to bf16 pairs ---
    unsigned w[8];
    #pragma unroll
    for (int i = 0; i < 8; ++i)
      asm("v_cvt_pk_bf16_f32 %0, %1, %2" : "=v"(w[i]) : "v"(p[2 * i]), "v"(p[2 * i + 1]));
    // --- two PV k-slices (kv 0..15, 16..31) ---
    __builtin_amdgcn_s_setprio(1);
    #pragma unroll
    for (int s2 = 0; s2 < 2; ++s2) {
      int b = s2 * 4;
      unsigned sw0 = __shfl_xor(w[b + 0], 32);
      unsigned sw1 = __shfl_xor(w[b + 1], 32);
      unsigned sw2 = __shfl_xor(w[b + 2], 32);
      unsigned sw3 = __shfl_xor(w[b + 3], 32);
      union { unsigned u[4]; short8 s8; } pa;
      pa.u[0] = hi ? sw2 : w[b + 0];
      pa.u[1] = hi ? sw3 : w[b + 1];
      pa.u[2] = hi ? w[b + 2] : sw0;
      pa.u[3] = hi ? w[b + 3] : sw1;
      o0 = __builtin_amdgcn_mfma_f32_32x32x16_bf16(pa.s8, vf[s2 * 2 + 0], o0, 0, 0, 0);
      o1 = __builtin_amdgcn_mfma_f32_32x32x16_bf16(pa.s8, vf[s2 * 2 + 1], o1, 0, 0, 0);
    }
    __builtin_amdgcn_s_setprio(0);
    // --- rotate prefetched regs ---
    #pragma unroll
    for (int s = 0; s < 4; ++s) { kf[s] = kn[s]; vf[s] = vn[s]; }
  }
  // --- epilogue: combine l halves, divide, store ---
  float lt = l + __shfl_xor(l, 32);
  float linv = 1.0f / lt;
  #pragma unroll
  for (int r = 0; r < 16; ++r) {
    int ql = (r & 3) + 8 * (r >> 2) + 4 * hi;
    float li = __shfl(linv, ql);
    int row = q0 + ql;
    attnout[row * DIM + h * HD + lq]      = f2bf(o0[r] * li);
    attnout[row * DIM + h * HD + 32 + lq] = f2bf(o1[r] * li);
  }
}

// ---------------------------------------------------------------------------
extern "C" void kernel_launch(void* const* d_in, const int* in_sizes, int n_in,
                              void* d_out, int out_size, void* d_ws, size_t ws_size,
                              hipStream_t stream) {
  const float* hs = (const float*)d_in[0];
  const float* wq = (const float*)d_in[1];
  const float* wk = (const float*)d_in[2];
  const float* wv = (const float*)d_in[3];
  const float* wo = (const float*)d_in[4];
  const int* pos  = (const int*)d_in[5];
  float* out = (float*)d_out;

  char* ws = (char*)d_ws;
  unsigned short* wqkvT = (unsigned short*)(ws);                    // 12582912 B
  unsigned short* woT   = (unsigned short*)(ws + 12582912);         //  8388608 B
  unsigned short* hbf   = (unsigned short*)(ws + 20971520);         //  8388608 B
  unsigned short* xqkv  = (unsigned short*)(ws + 29360128);         // 12582912 B
  unsigned short* xq    = (unsigned short*)(ws + 41943040);         //  8388608 B
  unsigned short* xk    = (unsigned short*)(ws + 50331648);         //  2097152 B
  unsigned short* xvT   = (unsigned short*)(ws + 52428800);         //  2097152 B
  f32x2*          tab   = (f32x2*)(ws + 54525952);                  //   524288 B
  unsigned short* attnout = hbf;  // hbf dead after first GEMM — reuse

  k_cast<<<4096, 256, 0, stream>>>(hs, hbf, SEQ * DIM);
  k_tcast<<<dim3(64, 64), dim3(32, 8), 0, stream>>>(wq, 2048, wqkvT);
  k_tcast<<<dim3(16, 64), dim3(32, 8), 0, stream>>>(wk, 512, wqkvT + 2048 * 2048);
  k_tcast<<<dim3(16, 64), dim3(32, 8), 0, stream>>>(wv, 512, wqkvT + 2560 * 2048);
  k_tcast<<<dim3(64, 64), dim3(32, 8), 0, stream>>>(wo, 2048, woT);
  k_table<<<256, 256, 0, stream>>>(pos, tab);

  k_gemm<NQKV, false><<<dim3(NQKV / 128, SEQ / 128), 512, 0, stream>>>(hbf, wqkvT, xqkv);

  k_rope<<<dim3(5, SEQ), 256, 0, stream>>>(xqkv, tab, xq, xk);
  k_vt<<<dim3(16, 64), dim3(32, 8), 0, stream>>>(xqkv, xvT);

  k_attn<<<512, 256, 0, stream>>>(xq, xk, xvT, attnout);

  k_gemm<DIM, true><<<dim3(DIM / 128, SEQ / 128), 512, 0, stream>>>(attnout, woT, out);
}

// Round 8
// 282.641 us; speedup vs baseline: 1.0772x; 1.0772x over previous
//
#include <hip/hip_runtime.h>
#include <hip/hip_bf16.h>

// ---------------------------------------------------------------------------
// Fused FlaxLLaMAAttention for MI355X (gfx950).
// B=1 S=2048 D=2048 H=32 KVH=8 HD=64, fp32 in/out, bf16 MFMA internals.
//
// Round 8:
//  - k_attn: KV-range SPLIT across 2 waves per (head, q-block) + {j,63-j}
//    pairing -> 2048 perfectly uniform ~33-step waves (halves the serial
//    critical path of the longest wave). LDS merge of (m,l,O) partials once
//    per phase. K+V reg prefetch, exp2 softmax, setprio kept from R4.
//  - k_gemm: reverted to the round-3 m97 structure (4 waves, 32KB LDS,
//    single buffer) -- the 64KB dbuf variant cut occupancy (m132 mode).
// ---------------------------------------------------------------------------

using short8  = __attribute__((ext_vector_type(8))) short;
using f32x4   = __attribute__((ext_vector_type(4))) float;
using f32x16  = __attribute__((ext_vector_type(16))) float;
using f32x2   = __attribute__((ext_vector_type(2))) float;
using ushort4v= __attribute__((ext_vector_type(4))) unsigned short;

#define SEQ 2048
#define DIM 2048
#define NH  32
#define NKVH 8
#define HD  64
#define KVD 512      // NKVH*HD
#define NQKV 3072    // DIM + 2*KVD

#define GLOAD_LDS16(g, l) \
  __builtin_amdgcn_global_load_lds((const __attribute__((address_space(1))) void*)(g), \
                                   (__attribute__((address_space(3))) void*)(l), 16, 0, 0)

__device__ __forceinline__ float bf2f(unsigned short u) {
  union { float f; unsigned v; } x; x.v = ((unsigned)u) << 16; return x.f;
}
__device__ __forceinline__ unsigned short f2bf(float f) {
  union { float f; unsigned v; } x; x.f = f;
  unsigned r = x.v + 0x7fffu + ((x.v >> 16) & 1u);   // round-nearest-even
  return (unsigned short)(r >> 16);
}

// ---------------- elementwise cast fp32 -> bf16 (vectorized) ----------------
__global__ __launch_bounds__(256) void k_cast(const float* __restrict__ src,
                                              unsigned short* __restrict__ dst, int n) {
  int idx = (blockIdx.x * 256 + threadIdx.x) * 4;
  if (idx < n) {
    f32x4 v = *(const f32x4*)(src + idx);
    ushort4v o;
    o[0] = f2bf(v[0]); o[1] = f2bf(v[1]); o[2] = f2bf(v[2]); o[3] = f2bf(v[3]);
    *(ushort4v*)(dst + idx) = o;
  }
}

// ---------------- transpose + cast: src fp32 [R=2048][C] -> dst bf16 [C][2048]
__global__ __launch_bounds__(256) void k_tcast(const float* __restrict__ src, int C,
                                               unsigned short* __restrict__ dst) {
  __shared__ float tile[32][33];
  int c0 = blockIdx.x * 32, r0 = blockIdx.y * 32;
  int tx = threadIdx.x, ty = threadIdx.y;   // 32x8
  #pragma unroll
  for (int j = 0; j < 32; j += 8)
    tile[ty + j][tx] = src[(r0 + ty + j) * C + c0 + tx];
  __syncthreads();
  #pragma unroll
  for (int j = 0; j < 32; j += 8)
    dst[(c0 + ty + j) * 2048 + r0 + tx] = f2bf(tile[tx][ty + j]);
}

// ---------------- rope cos/sin table: tab[s][p] = (cos,sin)(pos[s]*freq_p) ---
__global__ __launch_bounds__(256) void k_table(const int* __restrict__ pos,
                                               f32x2* __restrict__ tab) {
  int i = blockIdx.x * 256 + threadIdx.x;   // 2048*32
  int s = i >> 5, p = i & 31;
  float freq = powf(10000.0f, -(float)(2 * p) / 64.0f);
  float ang = (float)pos[s] * freq;
  float sv, cv; sincosf(ang, &sv, &cv);
  f32x2 r; r[0] = cv; r[1] = sv;
  tab[i] = r;
}

// ---------------- bf16 GEMM: C[M=2048][N] = A[2048][2048] * Bt[N][2048]^T ----
// 128x128 tile, BK=64, 4 waves (2x2), 16x16x32 bf16 MFMA,
// global_load_lds width=16 staging (m97 structure; 32KB LDS -> high occupancy).
template <int N, bool OUTF32>
__global__ __launch_bounds__(256) void k_gemm(const unsigned short* __restrict__ A,
                                              const unsigned short* __restrict__ Bt,
                                              void* __restrict__ Cout) {
  const int K = 2048;
  __shared__ unsigned short lA[128 * 64];
  __shared__ unsigned short lB[128 * 64];
  int m0 = blockIdx.y * 128, n0 = blockIdx.x * 128;
  int t = threadIdx.x, lane = t & 63, wid = t >> 6;
  int wr = wid >> 1, wc = wid & 1;          // wave 64x64 sub-tile
  int lr = lane & 15, lg = lane >> 4;

  f32x4 acc[4][4] = {};

  for (int k0 = 0; k0 < K; k0 += 64) {
    #pragma unroll
    for (int j = 0; j < 4; ++j) {
      int idx = t + 256 * j, row = idx >> 3, c8 = idx & 7;
      GLOAD_LDS16(A  + (m0 + row) * K + k0 + c8 * 8, lA + idx * 8);
      GLOAD_LDS16(Bt + (n0 + row) * K + k0 + c8 * 8, lB + idx * 8);
    }
    __syncthreads();                         // vmcnt(0) drain + barrier
    #pragma unroll
    for (int kk = 0; kk < 64; kk += 32) {
      short8 af[4], bfr[4];
      #pragma unroll
      for (int i = 0; i < 4; ++i) {
        af[i]  = *(const short8*)(lA + (wr * 64 + i * 16 + lr) * 64 + kk + lg * 8);
        bfr[i] = *(const short8*)(lB + (wc * 64 + i * 16 + lr) * 64 + kk + lg * 8);
      }
      #pragma unroll
      for (int i = 0; i < 4; ++i)
        #pragma unroll
        for (int j = 0; j < 4; ++j)
          acc[i][j] = __builtin_amdgcn_mfma_f32_16x16x32_bf16(af[i], bfr[j], acc[i][j], 0, 0, 0);
    }
    __syncthreads();                         // compute done before next overwrite
  }
  // epilogue: C layout col=lane&15, row=(lane>>4)*4+reg  [verified m89/m91]
  #pragma unroll
  for (int i = 0; i < 4; ++i)
    #pragma unroll
    for (int j = 0; j < 4; ++j)
      #pragma unroll
      for (int r = 0; r < 4; ++r) {
        int row = m0 + wr * 64 + i * 16 + lg * 4 + r;
        int col = n0 + wc * 64 + j * 16 + lr;
        float v = acc[i][j][r];
        if constexpr (OUTF32) ((float*)Cout)[row * N + col] = v;
        else ((unsigned short*)Cout)[row * N + col] = f2bf(v);
      }
}

// ---------------- rope split: xqkv -> xq (roped, *0.125*log2e), xk (roped) ---
__global__ __launch_bounds__(256) void k_rope(const unsigned short* __restrict__ xqkv,
                                              const f32x2* __restrict__ tab,
                                              unsigned short* __restrict__ xq,
                                              unsigned short* __restrict__ xk) {
  int s = blockIdx.y;
  int j = blockIdx.x * 256 + threadIdx.x;   // 0..1279 pair index
  bool isq = j < 1024;
  int col = isq ? (2 * j) : (DIM + 2 * (j - 1024));
  int p = (col >> 1) & 31;
  f32x2 cs = tab[s * 32 + p];
  unsigned both = *(const unsigned*)(xqkv + s * NQKV + col);
  float a = bf2f((unsigned short)(both & 0xffff));
  float b = bf2f((unsigned short)(both >> 16));
  float ra = a * cs[0] - b * cs[1];
  float rb = a * cs[1] + b * cs[0];
  const float QS = 0.125f * 1.44269504088896f;  // 1/sqrt(64) * log2(e)
  if (isq) { ra *= QS; rb *= QS; }
  unsigned pk = (unsigned)f2bf(ra) | ((unsigned)f2bf(rb) << 16);
  if (isq) *(unsigned*)(xq + s * DIM + col) = pk;
  else     *(unsigned*)(xk + s * KVD + (col - DIM)) = pk;
}

// ---------------- v transpose: xqkv cols [2560,3072) -> xvT [512][2048] ------
__global__ __launch_bounds__(256) void k_vt(const unsigned short* __restrict__ xqkv,
                                            unsigned short* __restrict__ xvT) {
  __shared__ unsigned short tile[32][33];
  int c0 = blockIdx.x * 32, s0 = blockIdx.y * 32;
  int tx = threadIdx.x, ty = threadIdx.y;   // 32x8
  #pragma unroll
  for (int j = 0; j < 32; j += 8)
    tile[ty + j][tx] = xqkv[(s0 + ty + j) * NQKV + 2560 + c0 + tx];
  __syncthreads();
  #pragma unroll
  for (int j = 0; j < 32; j += 8)
    xvT[(c0 + ty + j) * SEQ + s0 + tx] = tile[tx][ty + j];
}

// ---------------- causal GQA flash attention: split-KV, uniform waves -------
// 256 blocks x 8 waves. Block = (kvh, pair j). Wave = (head h3, kv-half).
// Each wave runs both phases (qb=j then qb=63-j) on its KV half-range:
// total tiles/wave = 32 or 33 (uniform). Partials merged in LDS per phase.
__global__ __launch_bounds__(512) void k_attn(const unsigned short* __restrict__ xq,
                                              const unsigned short* __restrict__ xk,
                                              const unsigned short* __restrict__ xvT,
                                              unsigned short* __restrict__ attnout) {
  __shared__ float obuf[4][64 * 36];        // per-head O exchange (stride 36 = conflict-light)
  __shared__ float sm_m[4][2][32];
  __shared__ float sm_l[4][32];

  int wid = threadIdx.x >> 6, lane = threadIdx.x & 63;
  int kvh = blockIdx.x & 7, j = blockIdx.x >> 3;   // j in 0..31
  int h3 = wid & 3, half = wid >> 2;
  int h = kvh * 4 + h3;
  int lq = lane & 31, hi = lane >> 5;

  auto loadK = [&](int kv0, short8* d) {
    #pragma unroll
    for (int s = 0; s < 4; ++s)
      d[s] = *(const short8*)(xk + (kv0 + lq) * KVD + kvh * HD + s * 16 + hi * 8);
  };
  auto loadV = [&](int kv0, short8* d) {
    #pragma unroll
    for (int s2 = 0; s2 < 2; ++s2) {
      d[s2 * 2 + 0] = *(const short8*)(xvT + (kvh * HD + lq)      * SEQ + kv0 + s2 * 16 + hi * 8);
      d[s2 * 2 + 1] = *(const short8*)(xvT + (kvh * HD + 32 + lq) * SEQ + kv0 + s2 * 16 + hi * 8);
    }
  };

  #pragma unroll 1
  for (int ph = 0; ph < 2; ++ph) {
    int qb = ph ? (63 - j) : j;
    int q0 = qb * 32;
    int T = qb + 1;                 // total kv tiles for this q-block
    int c0 = (T + 1) >> 1;          // split point
    int t0 = half ? c0 : 0;
    int t1 = half ? T : c0;

    // Q B-frags: lane holds q-row q0+lq, k = s*16 + hi*8 + [0..7]
    short8 qf[4];
    #pragma unroll
    for (int s = 0; s < 4; ++s)
      qf[s] = *(const short8*)(xq + (q0 + lq) * DIM + h * HD + s * 16 + hi * 8);

    f32x16 o0 = {}, o1 = {};
    float m = -3.0e38f, l = 0.0f;

    if (t0 < t1) {
      short8 kf[4], vf[4];
      loadK(t0 * 32, kf); loadV(t0 * 32, vf);

      for (int t = t0; t < t1; ++t) {
        int kv0 = t * 32;
        int kvn = min(t + 1, t1 - 1) * 32;   // clamped prefetch
        short8 kn[4], vn[4];
        loadK(kvn, kn); loadV(kvn, vn);

        // --- S^T = K Q^T : col=lq(q), row(kv) = (r&3)+8*(r>>2)+4*hi ---
        f32x16 st = {};
        __builtin_amdgcn_s_setprio(1);
        #pragma unroll
        for (int s = 0; s < 4; ++s)
          st = __builtin_amdgcn_mfma_f32_32x32x16_bf16(kf[s], qf[s], st, 0, 0, 0);
        __builtin_amdgcn_s_setprio(0);

        // --- causal mask (diagonal tile only; always in half1 unless T==1) ---
        if (kv0 == q0) {
          #pragma unroll
          for (int r = 0; r < 16; ++r) {
            int kvl = (r & 3) + 8 * (r >> 2) + 4 * hi;
            if (kvl > lq) st[r] = -3.0e38f;
          }
        }
        // --- row max ---
        float pmax = st[0];
        #pragma unroll
        for (int r = 1; r < 16; ++r) pmax = fmaxf(pmax, st[r]);
        pmax = fmaxf(pmax, __shfl_xor(pmax, 32));
        // --- defer-max rescale (bound 2^11.54 ~= e^8) ---
        if (!__all(pmax - m <= 11.54f)) {
          float mnew = fmaxf(m, pmax);
          float scale = exp2f(m - mnew);
          #pragma unroll
          for (int r = 0; r < 16; ++r) {
            int ql = (r & 3) + 8 * (r >> 2) + 4 * hi;
            float sc = __shfl(scale, ql);
            o0[r] *= sc; o1[r] *= sc;
          }
          l *= scale;
          m = mnew;
        }
        // --- P = exp2(S' - m), partial row-sum ---
        float p[16], sum = 0.0f;
        #pragma unroll
        for (int r = 0; r < 16; ++r) { p[r] = exp2f(st[r] - m); sum += p[r]; }
        l += sum;
        // --- pack to bf16 pairs ---
        unsigned w[8];
        #pragma unroll
        for (int i = 0; i < 8; ++i)
          asm("v_cvt_pk_bf16_f32 %0, %1, %2" : "=v"(w[i]) : "v"(p[2 * i]), "v"(p[2 * i + 1]));
        // --- two PV k-slices ---
        __builtin_amdgcn_s_setprio(1);
        #pragma unroll
        for (int s2 = 0; s2 < 2; ++s2) {
          int b = s2 * 4;
          unsigned sw0 = __shfl_xor(w[b + 0], 32);
          unsigned sw1 = __shfl_xor(w[b + 1], 32);
          unsigned sw2 = __shfl_xor(w[b + 2], 32);
          unsigned sw3 = __shfl_xor(w[b + 3], 32);
          union { unsigned u[4]; short8 s8; } pa;
          pa.u[0] = hi ? sw2 : w[b + 0];
          pa.u[1] = hi ? sw3 : w[b + 1];
          pa.u[2] = hi ? w[b + 2] : sw0;
          pa.u[3] = hi ? w[b + 3] : sw1;
          o0 = __builtin_amdgcn_mfma_f32_32x32x16_bf16(pa.s8, vf[s2 * 2 + 0], o0, 0, 0, 0);
          o1 = __builtin_amdgcn_mfma_f32_32x32x16_bf16(pa.s8, vf[s2 * 2 + 1], o1, 0, 0, 0);
        }
        __builtin_amdgcn_s_setprio(0);
        #pragma unroll
        for (int s = 0; s < 4; ++s) { kf[s] = kn[s]; vf[s] = vn[s]; }
      }
    }

    // ---- merge the two kv-halves for this (head, qb) via LDS ----
    float lc = l + __shfl_xor(l, 32);       // per-q combined partial sum
    if (hi == 0) sm_m[h3][half][lq] = m;
    __syncthreads();
    float mo = sm_m[h3][half ^ 1][lq];
    float mstar = fmaxf(m, mo);
    float s = exp2f(m - mstar);             // 0 if this half was empty
    if (half) {
      if (hi == 0) sm_l[h3][lq] = lc * s;
      float* ob = &obuf[h3][lane * 36];
      #pragma unroll
      for (int r = 0; r < 16; ++r) {
        int ql = (r & 3) + 8 * (r >> 2) + 4 * hi;
        float sc = __shfl(s, ql);
        ob[r] = o0[r] * sc;
        ob[16 + r] = o1[r] * sc;
      }
    }
    __syncthreads();
    if (!half) {
      float lB = sm_l[h3][lq];
      float ltot = lc * s + lB;
      float linv = 1.0f / ltot;
      const float* ob = &obuf[h3][lane * 36];
      #pragma unroll
      for (int r = 0; r < 16; ++r) {
        int ql = (r & 3) + 8 * (r >> 2) + 4 * hi;
        float sc = __shfl(s, ql);
        float li = __shfl(linv, ql);
        int row = q0 + ql;
        attnout[row * DIM + h * HD + lq]      = f2bf((o0[r] * sc + ob[r]) * li);
        attnout[row * DIM + h * HD + 32 + lq] = f2bf((o1[r] * sc + ob[16 + r]) * li);
      }
    }
    if (ph == 0) __syncthreads();           // buffers reused in phase 1
  }
}

// ---------------------------------------------------------------------------
extern "C" void kernel_launch(void* const* d_in, const int* in_sizes, int n_in,
                              void* d_out, int out_size, void* d_ws, size_t ws_size,
                              hipStream_t stream) {
  const float* hs = (const float*)d_in[0];
  const float* wq = (const float*)d_in[1];
  const float* wk = (const float*)d_in[2];
  const float* wv = (const float*)d_in[3];
  const float* wo = (const float*)d_in[4];
  const int* pos  = (const int*)d_in[5];
  float* out = (float*)d_out;

  char* ws = (char*)d_ws;
  unsigned short* wqkvT = (unsigned short*)(ws);                    // 12582912 B
  unsigned short* woT   = (unsigned short*)(ws + 12582912);         //  8388608 B
  unsigned short* hbf   = (unsigned short*)(ws + 20971520);         //  8388608 B
  unsigned short* xqkv  = (unsigned short*)(ws + 29360128);         // 12582912 B
  unsigned short* xq    = (unsigned short*)(ws + 41943040);         //  8388608 B
  unsigned short* xk    = (unsigned short*)(ws + 50331648);         //  2097152 B
  unsigned short* xvT   = (unsigned short*)(ws + 52428800);         //  2097152 B
  f32x2*          tab   = (f32x2*)(ws + 54525952);                  //   524288 B
  unsigned short* attnout = hbf;  // hbf dead after first GEMM — reuse

  k_cast<<<4096, 256, 0, stream>>>(hs, hbf, SEQ * DIM);
  k_tcast<<<dim3(64, 64), dim3(32, 8), 0, stream>>>(wq, 2048, wqkvT);
  k_tcast<<<dim3(16, 64), dim3(32, 8), 0, stream>>>(wk, 512, wqkvT + 2048 * 2048);
  k_tcast<<<dim3(16, 64), dim3(32, 8), 0, stream>>>(wv, 512, wqkvT + 2560 * 2048);
  k_tcast<<<dim3(64, 64), dim3(32, 8), 0, stream>>>(wo, 2048, woT);
  k_table<<<256, 256, 0, stream>>>(pos, tab);

  k_gemm<NQKV, false><<<dim3(NQKV / 128, SEQ / 128), 256, 0, stream>>>(hbf, wqkvT, xqkv);

  k_rope<<<dim3(5, SEQ), 256, 0, stream>>>(xqkv, tab, xq, xk);
  k_vt<<<dim3(16, 64), dim3(32, 8), 0, stream>>>(xqkv, xvT);

  k_attn<<<256, 512, 0, stream>>>(xq, xk, xvT, attnout);

  k_gemm<DIM, true><<<dim3(DIM / 128, SEQ / 128), 256, 0, stream>>>(attnout, woT, out);
}

// Round 9
// 264.251 us; speedup vs baseline: 1.1521x; 1.0696x over previous
//
#include <hip/hip_runtime.h>
#include <hip/hip_bf16.h>

// ---------------------------------------------------------------------------
// Fused FlaxLLaMAAttention for MI355X (gfx950).
// B=1 S=2048 D=2048 H=32 KVH=8 HD=64, fp32 in/out, bf16 MFMA internals.
//
// Round 9:
//  - k_attn: 512 blocks = (kvh, qb) x 8 waves (4 heads x 2 KV-halves).
//    K/V tiles staged in LDS ONCE per half-group (GQA 4x reuse) via
//    global_load_lds with pre-swizzled global source (m173 pattern),
//    double-buffered, XOR-swizzled ds_read_b128 fragment reads.
//    Uniform padded loops; R8-proven LDS merge of the two KV halves.
//  - k_gemm: m97 structure (4 waves, 32KB LDS, global_load_lds w16).
// ---------------------------------------------------------------------------

using short8  = __attribute__((ext_vector_type(8))) short;
using f32x4   = __attribute__((ext_vector_type(4))) float;
using f32x16  = __attribute__((ext_vector_type(16))) float;
using f32x2   = __attribute__((ext_vector_type(2))) float;
using ushort4v= __attribute__((ext_vector_type(4))) unsigned short;

#define SEQ 2048
#define DIM 2048
#define NH  32
#define NKVH 8
#define HD  64
#define KVD 512      // NKVH*HD
#define NQKV 3072    // DIM + 2*KVD

#define GLOAD_LDS16(g, l) \
  __builtin_amdgcn_global_load_lds((const __attribute__((address_space(1))) void*)(g), \
                                   (__attribute__((address_space(3))) void*)(l), 16, 0, 0)

__device__ __forceinline__ float bf2f(unsigned short u) {
  union { float f; unsigned v; } x; x.v = ((unsigned)u) << 16; return x.f;
}
__device__ __forceinline__ unsigned short f2bf(float f) {
  union { float f; unsigned v; } x; x.f = f;
  unsigned r = x.v + 0x7fffu + ((x.v >> 16) & 1u);   // round-nearest-even
  return (unsigned short)(r >> 16);
}

// ---------------- elementwise cast fp32 -> bf16 (vectorized) ----------------
__global__ __launch_bounds__(256) void k_cast(const float* __restrict__ src,
                                              unsigned short* __restrict__ dst, int n) {
  int idx = (blockIdx.x * 256 + threadIdx.x) * 4;
  if (idx < n) {
    f32x4 v = *(const f32x4*)(src + idx);
    ushort4v o;
    o[0] = f2bf(v[0]); o[1] = f2bf(v[1]); o[2] = f2bf(v[2]); o[3] = f2bf(v[3]);
    *(ushort4v*)(dst + idx) = o;
  }
}

// ---------------- transpose + cast: src fp32 [R=2048][C] -> dst bf16 [C][2048]
__global__ __launch_bounds__(256) void k_tcast(const float* __restrict__ src, int C,
                                               unsigned short* __restrict__ dst) {
  __shared__ float tile[32][33];
  int c0 = blockIdx.x * 32, r0 = blockIdx.y * 32;
  int tx = threadIdx.x, ty = threadIdx.y;   // 32x8
  #pragma unroll
  for (int j = 0; j < 32; j += 8)
    tile[ty + j][tx] = src[(r0 + ty + j) * C + c0 + tx];
  __syncthreads();
  #pragma unroll
  for (int j = 0; j < 32; j += 8)
    dst[(c0 + ty + j) * 2048 + r0 + tx] = f2bf(tile[tx][ty + j]);
}

// ---------------- rope cos/sin table: tab[s][p] = (cos,sin)(pos[s]*freq_p) ---
__global__ __launch_bounds__(256) void k_table(const int* __restrict__ pos,
                                               f32x2* __restrict__ tab) {
  int i = blockIdx.x * 256 + threadIdx.x;   // 2048*32
  int s = i >> 5, p = i & 31;
  float freq = powf(10000.0f, -(float)(2 * p) / 64.0f);
  float ang = (float)pos[s] * freq;
  float sv, cv; sincosf(ang, &sv, &cv);
  f32x2 r; r[0] = cv; r[1] = sv;
  tab[i] = r;
}

// ---------------- bf16 GEMM: C[M=2048][N] = A[2048][2048] * Bt[N][2048]^T ----
// 128x128 tile, BK=64, 4 waves (2x2), 16x16x32 bf16 MFMA,
// global_load_lds width=16 staging (m97 structure; 32KB LDS -> high occupancy).
template <int N, bool OUTF32>
__global__ __launch_bounds__(256) void k_gemm(const unsigned short* __restrict__ A,
                                              const unsigned short* __restrict__ Bt,
                                              void* __restrict__ Cout) {
  const int K = 2048;
  __shared__ unsigned short lA[128 * 64];
  __shared__ unsigned short lB[128 * 64];
  int m0 = blockIdx.y * 128, n0 = blockIdx.x * 128;
  int t = threadIdx.x, lane = t & 63, wid = t >> 6;
  int wr = wid >> 1, wc = wid & 1;          // wave 64x64 sub-tile
  int lr = lane & 15, lg = lane >> 4;

  f32x4 acc[4][4] = {};

  for (int k0 = 0; k0 < K; k0 += 64) {
    #pragma unroll
    for (int j = 0; j < 4; ++j) {
      int idx = t + 256 * j, row = idx >> 3, c8 = idx & 7;
      GLOAD_LDS16(A  + (m0 + row) * K + k0 + c8 * 8, lA + idx * 8);
      GLOAD_LDS16(Bt + (n0 + row) * K + k0 + c8 * 8, lB + idx * 8);
    }
    __syncthreads();                         // vmcnt(0) drain + barrier
    #pragma unroll
    for (int kk = 0; kk < 64; kk += 32) {
      short8 af[4], bfr[4];
      #pragma unroll
      for (int i = 0; i < 4; ++i) {
        af[i]  = *(const short8*)(lA + (wr * 64 + i * 16 + lr) * 64 + kk + lg * 8);
        bfr[i] = *(const short8*)(lB + (wc * 64 + i * 16 + lr) * 64 + kk + lg * 8);
      }
      #pragma unroll
      for (int i = 0; i < 4; ++i)
        #pragma unroll
        for (int j = 0; j < 4; ++j)
          acc[i][j] = __builtin_amdgcn_mfma_f32_16x16x32_bf16(af[i], bfr[j], acc[i][j], 0, 0, 0);
    }
    __syncthreads();                         // compute done before next overwrite
  }
  // epilogue: C layout col=lane&15, row=(lane>>4)*4+reg  [verified m89/m91]
  #pragma unroll
  for (int i = 0; i < 4; ++i)
    #pragma unroll
    for (int j = 0; j < 4; ++j)
      #pragma unroll
      for (int r = 0; r < 4; ++r) {
        int row = m0 + wr * 64 + i * 16 + lg * 4 + r;
        int col = n0 + wc * 64 + j * 16 + lr;
        float v = acc[i][j][r];
        if constexpr (OUTF32) ((float*)Cout)[row * N + col] = v;
        else ((unsigned short*)Cout)[row * N + col] = f2bf(v);
      }
}

// ---------------- rope split: xqkv -> xq (roped, *0.125*log2e), xk (roped) ---
__global__ __launch_bounds__(256) void k_rope(const unsigned short* __restrict__ xqkv,
                                              const f32x2* __restrict__ tab,
                                              unsigned short* __restrict__ xq,
                                              unsigned short* __restrict__ xk) {
  int s = blockIdx.y;
  int j = blockIdx.x * 256 + threadIdx.x;   // 0..1279 pair index
  bool isq = j < 1024;
  int col = isq ? (2 * j) : (DIM + 2 * (j - 1024));
  int p = (col >> 1) & 31;
  f32x2 cs = tab[s * 32 + p];
  unsigned both = *(const unsigned*)(xqkv + s * NQKV + col);
  float a = bf2f((unsigned short)(both & 0xffff));
  float b = bf2f((unsigned short)(both >> 16));
  float ra = a * cs[0] - b * cs[1];
  float rb = a * cs[1] + b * cs[0];
  const float QS = 0.125f * 1.44269504088896f;  // 1/sqrt(64) * log2(e)
  if (isq) { ra *= QS; rb *= QS; }
  unsigned pk = (unsigned)f2bf(ra) | ((unsigned)f2bf(rb) << 16);
  if (isq) *(unsigned*)(xq + s * DIM + col) = pk;
  else     *(unsigned*)(xk + s * KVD + (col - DIM)) = pk;
}

// ---------------- v transpose: xqkv cols [2560,3072) -> xvT [512][2048] ------
__global__ __launch_bounds__(256) void k_vt(const unsigned short* __restrict__ xqkv,
                                            unsigned short* __restrict__ xvT) {
  __shared__ unsigned short tile[32][33];
  int c0 = blockIdx.x * 32, s0 = blockIdx.y * 32;
  int tx = threadIdx.x, ty = threadIdx.y;   // 32x8
  #pragma unroll
  for (int j = 0; j < 32; j += 8)
    tile[ty + j][tx] = xqkv[(s0 + ty + j) * NQKV + 2560 + c0 + tx];
  __syncthreads();
  #pragma unroll
  for (int j = 0; j < 32; j += 8)
    xvT[(c0 + ty + j) * SEQ + s0 + tx] = tile[tx][ty + j];
}

// ---------------- causal GQA flash attention: LDS-staged K/V, split-KV ------
// 512 blocks = (kvh, qb) qb-descending; 8 waves = (4 heads h3) x (2 kv-halves).
// The 4 waves of a half share staged K (32x64, swz (r&7)<<4) and V (64x32,
// swz (r&3)<<4) LDS tiles, double-buffered, stage-before-compute. Softmax
// in-register exp2-domain; halves merged via LDS (R8-proven logic).
__global__ __launch_bounds__(512, 4) void k_attn(const unsigned short* __restrict__ xq,
                                                 const unsigned short* __restrict__ xk,
                                                 const unsigned short* __restrict__ xvT,
                                                 unsigned short* __restrict__ attnout) {
  __shared__ __align__(16) char smem[38400];
  // staging (loop): K[half][buf] @ half*8192+buf*4096 (4KB), V @ +16384 (4KB)
  // merge  (after): obuf [4][64*36] f32 @0 (36864B), sm_m @36864, sm_l @37888

  int wid = threadIdx.x >> 6, lane = threadIdx.x & 63;
  int kvh = blockIdx.x & 7, qb = 63 - (blockIdx.x >> 3);
  int h3 = wid & 3, half = wid >> 2;
  int h = kvh * 4 + h3;
  int lq = lane & 31, hi = lane >> 5;
  int q0 = qb * 32, T = qb + 1, c0 = (T + 1) >> 1;
  int t0 = half ? c0 : 0, t1 = half ? T : c0, P = c0;

  auto stageKV = [&](int tile, int buf) {
    int kv0 = tile * 32;
    // K quarter: wave h3 stages rows h3*8..+7; pre-swizzled global col
    int rl = lane >> 3;                                   // 0..7
    const unsigned short* ks = xk + (kv0 + h3 * 8 + rl) * KVD + kvh * HD
                                  + (((lane & 7) ^ rl) << 3);
    GLOAD_LDS16(ks, smem + half * 8192 + buf * 4096 + h3 * 1024 + lane * 16);
    // V quarter: wave h3 stages d-rows h3*16..+15
    int dl = lane >> 2;                                   // 0..15
    const unsigned short* vs = xvT + (kvh * HD + h3 * 16 + dl) * SEQ + kv0
                                   + (((lane & 3) ^ (dl & 3)) << 3);
    GLOAD_LDS16(vs, smem + 16384 + half * 8192 + buf * 4096 + h3 * 1024 + lane * 16);
  };

  // Q B-frags: lane holds q-row q0+lq, k = s*16 + hi*8 + [0..7]
  short8 qf[4];
  #pragma unroll
  for (int s = 0; s < 4; ++s)
    qf[s] = *(const short8*)(xq + (q0 + lq) * DIM + h * HD + s * 16 + hi * 8);

  f32x16 o0 = {}, o1 = {};
  float m = -3.0e38f, l = 0.0f;

  stageKV(t0 < t1 ? t0 : 0, 0);
  __syncthreads();
  int cur = 0;

  for (int i = 0; i < P; ++i) {
    int t = t0 + i;
    if (i + 1 < P) {                         // uniform across block
      int tt = t0 + i + 1;
      int tmax = (t1 > t0) ? (t1 - 1) : 0;
      if (tt > tmax) tt = tmax;
      stageKV(tt, cur ^ 1);
    }
    if (t < t1) {                            // uniform per wave (skip dummy)
      int kv0 = t * 32;
      const char* Kb = smem + half * 8192 + cur * 4096;
      const char* Vb = smem + 16384 + half * 8192 + cur * 4096;
      short8 kf[4], vf[4];
      #pragma unroll
      for (int s = 0; s < 4; ++s)
        kf[s] = *(const short8*)(Kb + lq * 128 + ((s * 32 + hi * 16) ^ ((lq & 7) << 4)));
      vf[0] = *(const short8*)(Vb + lq * 64        + ((hi * 16)      ^ ((lq & 3) << 4)));
      vf[1] = *(const short8*)(Vb + (32 + lq) * 64 + ((hi * 16)      ^ ((lq & 3) << 4)));
      vf[2] = *(const short8*)(Vb + lq * 64        + ((32 + hi * 16) ^ ((lq & 3) << 4)));
      vf[3] = *(const short8*)(Vb + (32 + lq) * 64 + ((32 + hi * 16) ^ ((lq & 3) << 4)));

      // --- S^T = K Q^T : col=lq(q), row(kv) = (r&3)+8*(r>>2)+4*hi ---
      f32x16 st = {};
      __builtin_amdgcn_s_setprio(1);
      #pragma unroll
      for (int s = 0; s < 4; ++s)
        st = __builtin_amdgcn_mfma_f32_32x32x16_bf16(kf[s], qf[s], st, 0, 0, 0);
      __builtin_amdgcn_s_setprio(0);

      // --- causal mask (diagonal tile only) ---
      if (kv0 == q0) {
        #pragma unroll
        for (int r = 0; r < 16; ++r) {
          int kvl = (r & 3) + 8 * (r >> 2) + 4 * hi;
          if (kvl > lq) st[r] = -3.0e38f;
        }
      }
      // --- row max ---
      float pmax = st[0];
      #pragma unroll
      for (int r = 1; r < 16; ++r) pmax = fmaxf(pmax, st[r]);
      pmax = fmaxf(pmax, __shfl_xor(pmax, 32));
      // --- defer-max rescale (bound 2^11.54 ~= e^8) ---
      if (!__all(pmax - m <= 11.54f)) {
        float mnew = fmaxf(m, pmax);
        float scale = exp2f(m - mnew);
        #pragma unroll
        for (int r = 0; r < 16; ++r) {
          int ql = (r & 3) + 8 * (r >> 2) + 4 * hi;
          float sc = __shfl(scale, ql);
          o0[r] *= sc; o1[r] *= sc;
        }
        l *= scale;
        m = mnew;
      }
      // --- P = exp2(S' - m), partial row-sum ---
      float p[16], sum = 0.0f;
      #pragma unroll
      for (int r = 0; r < 16; ++r) { p[r] = exp2f(st[r] - m); sum += p[r]; }
      l += sum;
      // --- pack to bf16 pairs ---
      unsigned w[8];
      #pragma unroll
      for (int i2 = 0; i2 < 8; ++i2)
        asm("v_cvt_pk_bf16_f32 %0, %1, %2" : "=v"(w[i2]) : "v"(p[2 * i2]), "v"(p[2 * i2 + 1]));
      // --- two PV k-slices ---
      __builtin_amdgcn_s_setprio(1);
      #pragma unroll
      for (int s2 = 0; s2 < 2; ++s2) {
        int b = s2 * 4;
        unsigned sw0 = __shfl_xor(w[b + 0], 32);
        unsigned sw1 = __shfl_xor(w[b + 1], 32);
        unsigned sw2 = __shfl_xor(w[b + 2], 32);
        unsigned sw3 = __shfl_xor(w[b + 3], 32);
        union { unsigned u[4]; short8 s8; } pa;
        pa.u[0] = hi ? sw2 : w[b + 0];
        pa.u[1] = hi ? sw3 : w[b + 1];
        pa.u[2] = hi ? w[b + 2] : sw0;
        pa.u[3] = hi ? w[b + 3] : sw1;
        o0 = __builtin_amdgcn_mfma_f32_32x32x16_bf16(pa.s8, vf[s2 * 2 + 0], o0, 0, 0, 0);
        o1 = __builtin_amdgcn_mfma_f32_32x32x16_bf16(pa.s8, vf[s2 * 2 + 1], o1, 0, 0, 0);
      }
      __builtin_amdgcn_s_setprio(0);
    }
    __syncthreads();                         // all reads done before overwrite
    cur ^= 1;
  }

  // ---- merge the two kv-halves for this (head, qb) via LDS (R8 logic) ----
  float* obufp = (float*)smem;               // [4][64*36]
  float* smm   = (float*)(smem + 36864);     // [4][2][32]
  float* sml   = (float*)(smem + 37888);     // [4][32]

  float lc = l + __shfl_xor(l, 32);          // per-q combined partial sum
  if (hi == 0) smm[h3 * 64 + half * 32 + lq] = m;
  __syncthreads();
  float mo = smm[h3 * 64 + (half ^ 1) * 32 + lq];
  float mstar = fmaxf(m, mo);
  float s = exp2f(m - mstar);                // 0 if this half was empty
  if (half) {
    if (hi == 0) sml[h3 * 32 + lq] = lc * s;
    float* ob = obufp + h3 * 2304 + lane * 36;
    #pragma unroll
    for (int r = 0; r < 16; ++r) {
      int ql = (r & 3) + 8 * (r >> 2) + 4 * hi;
      float sc = __shfl(s, ql);
      ob[r] = o0[r] * sc;
      ob[16 + r] = o1[r] * sc;
    }
  }
  __syncthreads();
  if (!half) {
    float lB = sml[h3 * 32 + lq];
    float ltot = lc * s + lB;
    float linv = 1.0f / ltot;
    const float* ob = obufp + h3 * 2304 + lane * 36;
    #pragma unroll
    for (int r = 0; r < 16; ++r) {
      int ql = (r & 3) + 8 * (r >> 2) + 4 * hi;
      float sc = __shfl(s, ql);
      float li = __shfl(linv, ql);
      int row = q0 + ql;
      attnout[row * DIM + h * HD + lq]      = f2bf((o0[r] * sc + ob[r]) * li);
      attnout[row * DIM + h * HD + 32 + lq] = f2bf((o1[r] * sc + ob[16 + r]) * li);
    }
  }
}

// ---------------------------------------------------------------------------
extern "C" void kernel_launch(void* const* d_in, const int* in_sizes, int n_in,
                              void* d_out, int out_size, void* d_ws, size_t ws_size,
                              hipStream_t stream) {
  const float* hs = (const float*)d_in[0];
  const float* wq = (const float*)d_in[1];
  const float* wk = (const float*)d_in[2];
  const float* wv = (const float*)d_in[3];
  const float* wo = (const float*)d_in[4];
  const int* pos  = (const int*)d_in[5];
  float* out = (float*)d_out;

  char* ws = (char*)d_ws;
  unsigned short* wqkvT = (unsigned short*)(ws);                    // 12582912 B
  unsigned short* woT   = (unsigned short*)(ws + 12582912);         //  8388608 B
  unsigned short* hbf   = (unsigned short*)(ws + 20971520);         //  8388608 B
  unsigned short* xqkv  = (unsigned short*)(ws + 29360128);         // 12582912 B
  unsigned short* xq    = (unsigned short*)(ws + 41943040);         //  8388608 B
  unsigned short* xk    = (unsigned short*)(ws + 50331648);         //  2097152 B
  unsigned short* xvT   = (unsigned short*)(ws + 52428800);         //  2097152 B
  f32x2*          tab   = (f32x2*)(ws + 54525952);                  //   524288 B
  unsigned short* attnout = hbf;  // hbf dead after first GEMM — reuse

  k_cast<<<4096, 256, 0, stream>>>(hs, hbf, SEQ * DIM);
  k_tcast<<<dim3(64, 64), dim3(32, 8), 0, stream>>>(wq, 2048, wqkvT);
  k_tcast<<<dim3(16, 64), dim3(32, 8), 0, stream>>>(wk, 512, wqkvT + 2048 * 2048);
  k_tcast<<<dim3(16, 64), dim3(32, 8), 0, stream>>>(wv, 512, wqkvT + 2560 * 2048);
  k_tcast<<<dim3(64, 64), dim3(32, 8), 0, stream>>>(wo, 2048, woT);
  k_table<<<256, 256, 0, stream>>>(pos, tab);

  k_gemm<NQKV, false><<<dim3(NQKV / 128, SEQ / 128), 256, 0, stream>>>(hbf, wqkvT, xqkv);

  k_rope<<<dim3(5, SEQ), 256, 0, stream>>>(xqkv, tab, xq, xk);
  k_vt<<<dim3(16, 64), dim3(32, 8), 0, stream>>>(xqkv, xvT);

  k_attn<<<512, 512, 0, stream>>>(xq, xk, xvT, attnout);

  k_gemm<DIM, true><<<dim3(DIM / 128, SEQ / 128), 256, 0, stream>>>(attnout, woT, out);
}